// Round 1
// baseline (289.824 us; speedup 1.0000x reference)
//
#include <hip/hip_runtime.h>
#include <math.h>

// Output layout (float32, concatenated in reference return order):
//   rendered [128,1,28,28]  -> offset 0,      size 100352
//   mu       [128,64]       -> offset 100352, size 8192
//   logvar   [128,64]       -> offset 108544, size 8192
//   cp       [128,2,3,4,2]  -> offset 116736, size 6144
//   widths   [128,2]        -> offset 122880, size 256
//   alphas   [128,2]        -> offset 123136, size 256
#define REND_OFF 0
#define MU_OFF   100352
#define LV_OFF   108544
#define CP_OFF   116736
#define W_OFF    122880
#define A_OFF    123136

__device__ __forceinline__ float leakyf(float x) {
    return x >= 0.f ? x : 0.2f * x;
}
__device__ __forceinline__ float seluf(float x) {
    const float sc = 1.0507009873554805f;
    const float al = 1.6732632423543772f;
    return x > 0.f ? sc * x : sc * al * expm1f(x);
}
__device__ __forceinline__ float sigmoidf(float x) {
    return 1.f / (1.f + expf(-x));
}

// One block (256 threads) per batch element. Full MLP chain fused; LDS holds
// all intermediates. Weights streamed from global (L2-resident, ~2.4MB).
__global__ __launch_bounds__(256) void vae_mlp(
    const float* __restrict__ x,    const float* __restrict__ eps,
    const float* __restrict__ e_w1, const float* __restrict__ e_b1,
    const float* __restrict__ e_w2, const float* __restrict__ e_b2,
    const float* __restrict__ w_mu, const float* __restrict__ b_mu,
    const float* __restrict__ w_lv, const float* __restrict__ b_lv,
    const float* __restrict__ d_w1, const float* __restrict__ d_b1,
    const float* __restrict__ d_w2, const float* __restrict__ d_b2,
    const float* __restrict__ p_w,  const float* __restrict__ p_b,
    const float* __restrict__ wd_w, const float* __restrict__ wd_b,
    const float* __restrict__ a_w,  const float* __restrict__ a_b,
    float* __restrict__ out)
{
    const int b   = blockIdx.x;
    const int tid = threadIdx.x;

    __shared__ float xs[784];
    __shared__ float h1[256];
    __shared__ float h2[256];
    __shared__ float zs[64];
    __shared__ float hd1[512];
    __shared__ float hd2[512];
    __shared__ float pts[40];

    for (int i = tid; i < 784; i += 256) xs[i] = x[b * 784 + i];
    __syncthreads();

    // encoder layer 1: 784 -> 256, leaky relu
    {
        float acc = e_b1[tid];
        #pragma unroll 8
        for (int k = 0; k < 784; ++k)
            acc = fmaf(xs[k], e_w1[k * 256 + tid], acc);
        h1[tid] = leakyf(acc);
    }
    __syncthreads();

    // encoder layer 2: 256 -> 256, leaky relu
    {
        float acc = e_b2[tid];
        #pragma unroll 8
        for (int k = 0; k < 256; ++k)
            acc = fmaf(h1[k], e_w2[k * 256 + tid], acc);
        h2[tid] = leakyf(acc);
    }
    __syncthreads();

    // mu / logvar (256 -> 64 each) + reparameterization
    if (tid < 64) {
        float am = b_mu[tid], al = b_lv[tid];
        #pragma unroll 8
        for (int k = 0; k < 256; ++k) {
            float h = h2[k];
            am = fmaf(h, w_mu[k * 64 + tid], am);
            al = fmaf(h, w_lv[k * 64 + tid], al);
        }
        out[MU_OFF + b * 64 + tid] = am;
        out[LV_OFF + b * 64 + tid] = al;
        zs[tid] = fmaf(eps[b * 64 + tid], expf(0.5f * al), am);
    }
    __syncthreads();

    // decoder layer 1: 64 -> 512, selu
    for (int j = tid; j < 512; j += 256) {
        float acc = d_b1[j];
        #pragma unroll
        for (int k = 0; k < 64; ++k)
            acc = fmaf(zs[k], d_w1[k * 512 + j], acc);
        hd1[j] = seluf(acc);
    }
    __syncthreads();

    // decoder layer 2: 512 -> 512, selu
    for (int j = tid; j < 512; j += 256) {
        float acc = d_b2[j];
        #pragma unroll 8
        for (int k = 0; k < 512; ++k)
            acc = fmaf(hd1[k], d_w2[k * 512 + j], acc);
        hd2[j] = seluf(acc);
    }
    __syncthreads();

    // heads: pts (40), widths (2), alphas (2); K = 512
    if (tid < 44) {
        const float* w;
        float bb;
        int stride;
        if (tid < 40)      { w = p_w  + tid;        bb = p_b[tid];       stride = 40; }
        else if (tid < 42) { w = wd_w + (tid - 40); bb = wd_b[tid - 40]; stride = 2;  }
        else               { w = a_w  + (tid - 42); bb = a_b[tid - 42];  stride = 2;  }
        float acc = bb;
        #pragma unroll 8
        for (int k = 0; k < 512; ++k)
            acc = fmaf(hd2[k], w[k * stride], acc);
        if (tid < 40) {
            pts[tid] = tanhf(acc) * 12.f + 14.f;   // CANVAS/2 - MARGIN = 12, +14
        } else if (tid < 42) {
            out[W_OFF + b * 2 + (tid - 40)] = sigmoidf(acc) * 2.f + 1.f;
        } else {
            out[A_OFF + b * 2 + (tid - 42)] = sigmoidf(acc);
        }
    }
    __syncthreads();

    // scatter cp [P=2, S=3, 4, 2] from pts [P=2, PPP=10, 2] (overlapping segs)
    if (tid < 48) {
        int p = tid / 24, rem = tid % 24;
        int s = rem / 8, kc = rem % 8;
        int k = kc >> 1, c = kc & 1;
        out[CP_OFF + b * 48 + tid] = pts[p * 20 + (3 * s + k) * 2 + c];
    }
}

// Render: grid (B=128, 4). Block (b,q) renders supersample rows [14q, 14q+14)
// => pixel rows [7q, 7q+7) of image b. Curve (192 pts) in LDS, broadcast-read.
__global__ __launch_bounds__(256) void vae_render(float* __restrict__ out)
{
    const int b   = blockIdx.x;
    const int q   = blockIdx.y;
    const int tid = threadIdx.x;

    __shared__ float2 cur[192];
    __shared__ float vals[784];
    __shared__ float sw0, sw1, sa0, sa1;

    if (tid < 192) {
        int p = tid / 96;
        int m = tid % 96;
        int s = m / 32;
        int t = m % 32;
        float u  = (t + 0.5f) * (1.f / 32.f);
        float v  = 1.f - u;
        float b0 = v * v * v;
        float b1 = 3.f * u * v * v;
        float b2 = 3.f * u * u * v;
        float b3 = u * u * u;
        const float* cp = out + CP_OFF + b * 48 + p * 24 + s * 8;
        float cx = b0 * cp[0] + b1 * cp[2] + b2 * cp[4] + b3 * cp[6];
        float cy = b0 * cp[1] + b1 * cp[3] + b2 * cp[5] + b3 * cp[7];
        cur[tid] = make_float2(cx, cy);
    }
    if (tid == 0) {
        sw0 = 0.5f * out[W_OFF + b * 2 + 0];
        sw1 = 0.5f * out[W_OFF + b * 2 + 1];
        sa0 = out[A_OFF + b * 2 + 0];
        sa1 = out[A_OFF + b * 2 + 1];
    }
    __syncthreads();

    const float w0 = sw0, w1 = sw1, a0 = sa0, a1 = sa1;

    for (int i = tid; i < 784; i += 256) {
        int sy = q * 14 + i / 56;
        int sx = i % 56;
        float px = (sx + 0.5f) * 0.5f;
        float py = (sy + 0.5f) * 0.5f;
        float m0 = 1e30f, m1 = 1e30f;
        #pragma unroll 8
        for (int m = 0; m < 96; ++m) {
            float2 c = cur[m];
            float dx = px - c.x, dy = py - c.y;
            m0 = fminf(m0, fmaf(dx, dx, dy * dy));
        }
        #pragma unroll 8
        for (int m = 96; m < 192; ++m) {
            float2 c = cur[m];
            float dx = px - c.x, dy = py - c.y;
            m1 = fminf(m1, fmaf(dx, dx, dy * dy));
        }
        float d0 = sqrtf(m0 + 1e-12f);
        float d1 = sqrtf(m1 + 1e-12f);
        // cov = sigmoid((w*0.5 - d)/0.5) = sigmoid(2*(hw - d))
        float c0 = a0 / (1.f + expf(-2.f * (w0 - d0)));
        float c1 = a1 / (1.f + expf(-2.f * (w1 - d1)));
        vals[i] = (1.f - c0) * (1.f - c1);
    }
    __syncthreads();

    // 2x2 pooling + (1 - img)
    if (tid < 196) {
        int Y = tid / 28, X = tid % 28;
        int base = (2 * Y) * 56 + 2 * X;
        float m = 0.25f * (vals[base] + vals[base + 1] + vals[base + 56] + vals[base + 57]);
        out[REND_OFF + b * 784 + (q * 7 + Y) * 28 + X] = 1.f - m;
    }
}

extern "C" void kernel_launch(void* const* d_in, const int* in_sizes, int n_in,
                              void* d_out, int out_size, void* d_ws, size_t ws_size,
                              hipStream_t stream) {
    const float* x    = (const float*)d_in[0];
    const float* eps  = (const float*)d_in[1];
    const float* e_w1 = (const float*)d_in[2];
    const float* e_b1 = (const float*)d_in[3];
    const float* e_w2 = (const float*)d_in[4];
    const float* e_b2 = (const float*)d_in[5];
    const float* w_mu = (const float*)d_in[6];
    const float* b_mu = (const float*)d_in[7];
    const float* w_lv = (const float*)d_in[8];
    const float* b_lv = (const float*)d_in[9];
    const float* d_w1 = (const float*)d_in[10];
    const float* d_b1 = (const float*)d_in[11];
    const float* d_w2 = (const float*)d_in[12];
    const float* d_b2 = (const float*)d_in[13];
    const float* p_w  = (const float*)d_in[14];
    const float* p_b  = (const float*)d_in[15];
    const float* wd_w = (const float*)d_in[16];
    const float* wd_b = (const float*)d_in[17];
    const float* a_w  = (const float*)d_in[18];
    const float* a_b  = (const float*)d_in[19];
    float* out = (float*)d_out;

    hipLaunchKernelGGL(vae_mlp, dim3(128), dim3(256), 0, stream,
                       x, eps, e_w1, e_b1, e_w2, e_b2, w_mu, b_mu, w_lv, b_lv,
                       d_w1, d_b1, d_w2, d_b2, p_w, p_b, wd_w, wd_b, a_w, a_b,
                       out);
    hipLaunchKernelGGL(vae_render, dim3(128, 4), dim3(256), 0, stream, out);
}

// Round 2
// 156.492 us; speedup vs baseline: 1.8520x; 1.8520x over previous
//
#include <hip/hip_runtime.h>
#include <math.h>

// Output layout (float32, concatenated in reference return order):
//   rendered [128,1,28,28]  -> offset 0,      size 100352
//   mu       [128,64]       -> offset 100352, size 8192
//   logvar   [128,64]       -> offset 108544, size 8192
//   cp       [128,2,3,4,2]  -> offset 116736, size 6144
//   widths   [128,2]        -> offset 122880, size 256
//   alphas   [128,2]        -> offset 123136, size 256
#define REND_OFF 0
#define MU_OFF   100352
#define LV_OFF   108544
#define CP_OFF   116736
#define W_OFF    122880
#define A_OFF    123136

__device__ __forceinline__ float leakyf(float x) {
    return x >= 0.f ? x : 0.2f * x;
}
__device__ __forceinline__ float seluf(float x) {
    const float sc = 1.0507009873554805f;
    const float al = 1.6732632423543772f;
    return x > 0.f ? sc * x : sc * al * expm1f(x);
}
__device__ __forceinline__ float sigmoidf(float x) {
    return 1.f / (1.f + expf(-x));
}

// 64 blocks x 1024 threads; block handles batch elements {2b, 2b+1}.
// Every layer: K-split across thread slices, 2 accumulators/thread (one per
// batch element, sharing each weight load), LDS tree reduce.
__global__ __launch_bounds__(1024) void vae_mlp(
    const float* __restrict__ x,    const float* __restrict__ eps,
    const float* __restrict__ e_w1, const float* __restrict__ e_b1,
    const float* __restrict__ e_w2, const float* __restrict__ e_b2,
    const float* __restrict__ w_mu, const float* __restrict__ b_mu,
    const float* __restrict__ w_lv, const float* __restrict__ b_lv,
    const float* __restrict__ d_w1, const float* __restrict__ d_b1,
    const float* __restrict__ d_w2, const float* __restrict__ d_b2,
    const float* __restrict__ p_w,  const float* __restrict__ p_b,
    const float* __restrict__ wd_w, const float* __restrict__ wd_b,
    const float* __restrict__ a_w,  const float* __restrict__ a_b,
    float* __restrict__ out)
{
    const int b0  = blockIdx.x * 2;
    const int tid = threadIdx.x;

    __shared__ float xs[1568];            // 2 x 784
    __shared__ float h1[2][256];
    __shared__ float h2[2][256];
    __shared__ float zs[2][64];
    __shared__ float hd1[2][512];
    __shared__ float hd2[2][512];
    __shared__ float red0[1024];
    __shared__ float red1[1024];
    __shared__ float mulv[2][128];        // [b][u]: u<64 mu, u>=64 logvar
    __shared__ float pts[2][40];

    for (int i = tid; i < 1568; i += 1024) xs[i] = x[b0 * 784 + i];
    __syncthreads();

    // ---- encoder layer 1: K=784 -> N=256, leaky. 4 K-slices of 196. ----
    {
        int j = tid & 255, ks = tid >> 8;
        const float* w = e_w1 + j;
        float a0 = 0.f, a1 = 0.f;
        int k0 = ks * 196;
        #pragma unroll 4
        for (int k = k0; k < k0 + 196; ++k) {
            float wv = w[k * 256];
            a0 = fmaf(xs[k], wv, a0);
            a1 = fmaf(xs[784 + k], wv, a1);
        }
        red0[tid] = a0; red1[tid] = a1;
    }
    __syncthreads();
    if (tid < 512) {
        int j = tid & 255, bs = tid >> 8;
        const float* r = bs ? red1 : red0;
        h1[bs][j] = leakyf(r[j] + r[256 + j] + r[512 + j] + r[768 + j] + e_b1[j]);
    }
    __syncthreads();

    // ---- encoder layer 2: K=256 -> N=256, leaky. 4 K-slices of 64. ----
    {
        int j = tid & 255, ks = tid >> 8;
        const float* w = e_w2 + j;
        float a0 = 0.f, a1 = 0.f;
        int k0 = ks * 64;
        #pragma unroll 4
        for (int k = k0; k < k0 + 64; ++k) {
            float wv = w[k * 256];
            a0 = fmaf(h1[0][k], wv, a0);
            a1 = fmaf(h1[1][k], wv, a1);
        }
        red0[tid] = a0; red1[tid] = a1;
    }
    __syncthreads();
    if (tid < 512) {
        int j = tid & 255, bs = tid >> 8;
        const float* r = bs ? red1 : red0;
        h2[bs][j] = leakyf(r[j] + r[256 + j] + r[512 + j] + r[768 + j] + e_b2[j]);
    }
    __syncthreads();

    // ---- mu/logvar: K=256 -> 64+64 units. 8 K-slices of 32. ----
    {
        int u = tid & 127, ks = tid >> 7;
        int j = u & 63;
        const float* w = (u < 64 ? w_mu : w_lv) + j;
        float a0 = 0.f, a1 = 0.f;
        int k0 = ks * 32;
        #pragma unroll 4
        for (int k = k0; k < k0 + 32; ++k) {
            float wv = w[k * 64];
            a0 = fmaf(h2[0][k], wv, a0);
            a1 = fmaf(h2[1][k], wv, a1);
        }
        red0[tid] = a0; red1[tid] = a1;
    }
    __syncthreads();
    if (tid < 256) {
        int u = tid & 127, bs = tid >> 7;
        const float* r = bs ? red1 : red0;
        float s = 0.f;
        #pragma unroll
        for (int si = 0; si < 8; ++si) s += r[si * 128 + u];
        int j = u & 63;
        s += (u < 64 ? b_mu[j] : b_lv[j]);
        mulv[bs][u] = s;
        out[(u < 64 ? MU_OFF : LV_OFF) + (b0 + bs) * 64 + j] = s;
    }
    __syncthreads();
    if (tid < 128) {
        int bs = tid >> 6, j = tid & 63;
        zs[bs][j] = fmaf(eps[(b0 + bs) * 64 + j], expf(0.5f * mulv[bs][64 + j]),
                         mulv[bs][j]);
    }
    __syncthreads();

    // ---- decoder layer 1: K=64 -> N=512, selu. No K-split. ----
    {
        int j = tid & 511, bs = tid >> 9;
        const float* zz = zs[bs];
        float a = d_b1[j];
        #pragma unroll
        for (int k = 0; k < 64; ++k)
            a = fmaf(zz[k], d_w1[k * 512 + j], a);
        hd1[bs][j] = seluf(a);
    }
    __syncthreads();

    // ---- decoder layer 2: K=512 -> N=512, selu. 2 K-slices of 256. ----
    {
        int j = tid & 511, ks = tid >> 9;
        const float* w = d_w2 + j;
        float a0 = 0.f, a1 = 0.f;
        int k0 = ks * 256;
        #pragma unroll 4
        for (int k = k0; k < k0 + 256; ++k) {
            float wv = w[k * 512];
            a0 = fmaf(hd1[0][k], wv, a0);
            a1 = fmaf(hd1[1][k], wv, a1);
        }
        red0[tid] = a0; red1[tid] = a1;
    }
    __syncthreads();
    {
        int j = tid & 511, bs = tid >> 9;
        const float* r = bs ? red1 : red0;
        hd2[bs][j] = seluf(r[j] + r[512 + j] + d_b2[j]);
    }
    __syncthreads();

    // ---- heads: K=512 -> 44 units. 16 K-slices of 32. ----
    {
        int u = tid & 63, ks = tid >> 6;
        float a0 = 0.f, a1 = 0.f;
        if (u < 44) {
            const float* w; int stride;
            if (u < 40)      { w = p_w + u;         stride = 40; }
            else if (u < 42) { w = wd_w + (u - 40); stride = 2;  }
            else             { w = a_w + (u - 42);  stride = 2;  }
            int k0 = ks * 32;
            #pragma unroll 4
            for (int k = k0; k < k0 + 32; ++k) {
                float wv = w[k * stride];
                a0 = fmaf(hd2[0][k], wv, a0);
                a1 = fmaf(hd2[1][k], wv, a1);
            }
        }
        red0[tid] = a0; red1[tid] = a1;
    }
    __syncthreads();
    if (tid < 128) {
        int u = tid & 63, bs = tid >> 6;
        if (u < 44) {
            const float* r = bs ? red1 : red0;
            float s = 0.f;
            #pragma unroll
            for (int si = 0; si < 16; ++si) s += r[si * 64 + u];
            if (u < 40) {
                pts[bs][u] = tanhf(s + p_b[u]) * 12.f + 14.f;  // CANVAS/2-MARGIN=12
            } else if (u < 42) {
                out[W_OFF + (b0 + bs) * 2 + (u - 40)] =
                    sigmoidf(s + wd_b[u - 40]) * 2.f + 1.f;
            } else {
                out[A_OFF + (b0 + bs) * 2 + (u - 42)] = sigmoidf(s + a_b[u - 42]);
            }
        }
    }
    __syncthreads();

    // scatter cp [P=2,S=3,4,2] from pts [P=2,PPP=10,2] (overlapping segments)
    if (tid < 96) {
        int bs = tid / 48, i = tid % 48;
        int p = i / 24, rem = i % 24;
        int s = rem / 8, kc = rem % 8;
        int k = kc >> 1, c = kc & 1;
        out[CP_OFF + (b0 + bs) * 48 + i] = pts[bs][p * 20 + (3 * s + k) * 2 + c];
    }
}

// Render: grid (128, 4), 256 threads. Block (b,q) -> pixel rows [7q, 7q+7).
// One pixel per thread (tid<196): 4 supersamples = 8 independent min-chains,
// shared dx/dy arithmetic (16 ops/curve-point instead of 24).
__global__ __launch_bounds__(256) void vae_render(float* __restrict__ out)
{
    const int b   = blockIdx.x;
    const int q   = blockIdx.y;
    const int tid = threadIdx.x;

    __shared__ float2 cur[192];
    __shared__ float  wa[4];   // 0,1: width*0.5; 2,3: alpha

    if (tid < 192) {
        int p = tid / 96;
        int m = tid % 96;
        int s = m / 32;
        int t = m % 32;
        float u  = (t + 0.5f) * (1.f / 32.f);
        float v  = 1.f - u;
        float b0 = v * v * v;
        float b1 = 3.f * u * v * v;
        float b2 = 3.f * u * u * v;
        float b3 = u * u * u;
        const float* cp = out + CP_OFF + b * 48 + p * 24 + s * 8;
        float cx = b0 * cp[0] + b1 * cp[2] + b2 * cp[4] + b3 * cp[6];
        float cy = b0 * cp[1] + b1 * cp[3] + b2 * cp[5] + b3 * cp[7];
        cur[tid] = make_float2(cx, cy);
    } else if (tid < 196) {
        int i = tid - 192;
        wa[i] = (i < 2) ? 0.5f * out[W_OFF + b * 2 + i]
                        : out[A_OFF + b * 2 + (i - 2)];
    }
    __syncthreads();

    if (tid < 196) {
        int Y = tid / 28, X = tid - Y * 28;
        float px0 = X + 0.25f;
        float py0 = (7 * q + Y) + 0.25f;

        float mA[4] = {1e30f, 1e30f, 1e30f, 1e30f};
        float mB[4] = {1e30f, 1e30f, 1e30f, 1e30f};
        #pragma unroll 4
        for (int m = 0; m < 96; ++m) {
            float2 c = cur[m];
            float dx0 = px0 - c.x, dy0 = py0 - c.y;
            float dx1 = dx0 + 0.5f, dy1 = dy0 + 0.5f;
            float xx0 = dx0 * dx0, xx1 = dx1 * dx1;
            float yy0 = dy0 * dy0, yy1 = dy1 * dy1;
            mA[0] = fminf(mA[0], xx0 + yy0);
            mA[1] = fminf(mA[1], xx1 + yy0);
            mA[2] = fminf(mA[2], xx0 + yy1);
            mA[3] = fminf(mA[3], xx1 + yy1);
        }
        #pragma unroll 4
        for (int m = 96; m < 192; ++m) {
            float2 c = cur[m];
            float dx0 = px0 - c.x, dy0 = py0 - c.y;
            float dx1 = dx0 + 0.5f, dy1 = dy0 + 0.5f;
            float xx0 = dx0 * dx0, xx1 = dx1 * dx1;
            float yy0 = dy0 * dy0, yy1 = dy1 * dy1;
            mB[0] = fminf(mB[0], xx0 + yy0);
            mB[1] = fminf(mB[1], xx1 + yy0);
            mB[2] = fminf(mB[2], xx0 + yy1);
            mB[3] = fminf(mB[3], xx1 + yy1);
        }

        const float w0 = wa[0], w1 = wa[1], a0 = wa[2], a1 = wa[3];
        float v = 0.f;
        #pragma unroll
        for (int s = 0; s < 4; ++s) {
            float d0 = sqrtf(mA[s] + 1e-12f);
            float d1 = sqrtf(mB[s] + 1e-12f);
            // cov = sigmoid((w*0.5 - d)/0.5) = sigmoid(2*(hw - d))
            float c0 = a0 / (1.f + expf(-2.f * (w0 - d0)));
            float c1 = a1 / (1.f + expf(-2.f * (w1 - d1)));
            v += (1.f - c0) * (1.f - c1);
        }
        out[REND_OFF + b * 784 + (7 * q + Y) * 28 + X] = 1.f - 0.25f * v;
    }
}

extern "C" void kernel_launch(void* const* d_in, const int* in_sizes, int n_in,
                              void* d_out, int out_size, void* d_ws, size_t ws_size,
                              hipStream_t stream) {
    const float* x    = (const float*)d_in[0];
    const float* eps  = (const float*)d_in[1];
    const float* e_w1 = (const float*)d_in[2];
    const float* e_b1 = (const float*)d_in[3];
    const float* e_w2 = (const float*)d_in[4];
    const float* e_b2 = (const float*)d_in[5];
    const float* w_mu = (const float*)d_in[6];
    const float* b_mu = (const float*)d_in[7];
    const float* w_lv = (const float*)d_in[8];
    const float* b_lv = (const float*)d_in[9];
    const float* d_w1 = (const float*)d_in[10];
    const float* d_b1 = (const float*)d_in[11];
    const float* d_w2 = (const float*)d_in[12];
    const float* d_b2 = (const float*)d_in[13];
    const float* p_w  = (const float*)d_in[14];
    const float* p_b  = (const float*)d_in[15];
    const float* wd_w = (const float*)d_in[16];
    const float* wd_b = (const float*)d_in[17];
    const float* a_w  = (const float*)d_in[18];
    const float* a_b  = (const float*)d_in[19];
    float* out = (float*)d_out;

    hipLaunchKernelGGL(vae_mlp, dim3(64), dim3(1024), 0, stream,
                       x, eps, e_w1, e_b1, e_w2, e_b2, w_mu, b_mu, w_lv, b_lv,
                       d_w1, d_b1, d_w2, d_b2, p_w, p_b, wd_w, wd_b, a_w, a_b,
                       out);
    hipLaunchKernelGGL(vae_render, dim3(128, 4), dim3(256), 0, stream, out);
}

// Round 3
// 134.426 us; speedup vs baseline: 2.1560x; 1.1641x over previous
//
#include <hip/hip_runtime.h>
#include <hip/hip_bf16.h>
#include <math.h>

// Output layout (float32, concatenated in reference return order):
//   rendered [128,1,28,28]  -> offset 0,      size 100352
//   mu       [128,64]       -> offset 100352, size 8192
//   logvar   [128,64]       -> offset 108544, size 8192
//   cp       [128,2,3,4,2]  -> offset 116736, size 6144
//   widths   [128,2]        -> offset 122880, size 256
//   alphas   [128,2]        -> offset 123136, size 256
#define REND_OFF 0
#define MU_OFF   100352
#define LV_OFF   108544
#define CP_OFF   116736
#define W_OFF    122880
#define A_OFF    123136

// bf16 weight workspace layout (element offsets; all row-major [K][N]):
//   W1  [784][256]          @ 0
//   W2  [256][256]          @ 200704
//   WML [256][128] (mu|lv)  @ 266240
//   WD1 [64][512]           @ 299008
//   WD2 [512][512]          @ 331776
//   WH  [512][64] (p|wd|a|0)@ 593920    total 626688 elems = 1.25 MB
#define WS_W1 0
#define WS_W2 200704
#define WS_ML 266240
#define WS_D1 299008
#define WS_D2 331776
#define WS_H  593920
#define WS_TOT 626688

__device__ __forceinline__ float leakyf(float x) {
    return x >= 0.f ? x : 0.2f * x;
}
__device__ __forceinline__ float seluf(float x) {
    const float sc = 1.0507009873554805f;
    const float al = 1.6732632423543772f;
    return x > 0.f ? sc * x : sc * al * expm1f(x);
}
__device__ __forceinline__ float sigmoidf(float x) {
    return 1.f / (1.f + expf(-x));
}
// unpack 2 bf16 (packed in uint32, little-endian) to fp32
__device__ __forceinline__ void bf2(unsigned u, float& lo, float& hi) {
    lo = __uint_as_float(u << 16);
    hi = __uint_as_float(u & 0xffff0000u);
}

// ---- kernel 0: convert fp32 weights -> bf16 workspace (fused/padded) ----
__global__ __launch_bounds__(256) void conv_w(
    const float* __restrict__ e_w1, const float* __restrict__ e_w2,
    const float* __restrict__ w_mu, const float* __restrict__ w_lv,
    const float* __restrict__ d_w1, const float* __restrict__ d_w2,
    const float* __restrict__ p_w,  const float* __restrict__ wd_w,
    const float* __restrict__ a_w,  __hip_bfloat16* __restrict__ ws)
{
    int i = blockIdx.x * 256 + threadIdx.x;
    if (i >= WS_TOT) return;
    float v;
    if (i < WS_W2) v = e_w1[i];
    else if (i < WS_ML) v = e_w2[i - WS_W2];
    else if (i < WS_D1) {
        int r = i - WS_ML, k = r >> 7, u = r & 127;
        v = (u < 64) ? w_mu[k * 64 + u] : w_lv[k * 64 + u - 64];
    }
    else if (i < WS_D2) v = d_w1[i - WS_D1];
    else if (i < WS_H)  v = d_w2[i - WS_D2];
    else {
        int r = i - WS_H, k = r >> 6, u = r & 63;
        v = (u < 40) ? p_w[k * 40 + u]
          : (u < 42) ? wd_w[k * 2 + u - 40]
          : (u < 44) ? a_w[k * 2 + u - 42] : 0.f;
    }
    ws[i] = (__hip_bfloat16)v;
}

// ---- kernel 1: fused MLP. 64 blocks x 1024 thr; 2 batch elems / block. ----
// Each layer: thread owns 4 adjacent output cols (uint2 = 4 bf16 / k-step),
// K split across wave-uniform slices, 8 accums (4j x 2b), padded LDS reduce.
__global__ __launch_bounds__(1024) void vae_mlp(
    const float* __restrict__ x,    const float* __restrict__ eps,
    const float* __restrict__ e_b1, const float* __restrict__ e_b2,
    const float* __restrict__ b_mu, const float* __restrict__ b_lv,
    const float* __restrict__ d_b1, const float* __restrict__ d_b2,
    const float* __restrict__ p_b,  const float* __restrict__ wd_b,
    const float* __restrict__ a_b,
    const __hip_bfloat16* __restrict__ ws, float* __restrict__ out)
{
    const int b0  = blockIdx.x * 2;
    const int tid = threadIdx.x;

    __shared__ float xs[784 * 2];    // [k][b] interleaved
    __shared__ float h1[256 * 2];    // [k][b]
    __shared__ float h2[256 * 2];
    __shared__ float zs[64 * 2];
    __shared__ float hd1[512 * 2];
    __shared__ float hd2[512 * 2];
    __shared__ float mulv[2][128];
    __shared__ float pts[2][40];
    __shared__ float red[8704];      // max reduce buffer (heads: 2*64*68)

    // stage x interleaved: xs[k*2 + bb]
    for (int i = tid; i < 1568; i += 1024) {
        int bb = i / 784, k = i - bb * 784;
        xs[k * 2 + bb] = x[b0 * 784 + i];
    }
    __syncthreads();

    // ================= encoder L1: K=784, N=256, S=16 (49 k each) ========
    {
        int jg = tid & 63, ks = tid >> 6;
        const uint2* p = (const uint2*)(ws + WS_W1) + (ks * 49) * 64 + jg;
        const float* xp = xs + (ks * 49) * 2;
        float a0=0,a1=0,a2=0,a3=0,a4=0,a5=0,a6=0,a7=0;
        #pragma unroll 7
        for (int kk = 0; kk < 49; ++kk, p += 64) {
            uint2 w = *p;
            float w0,w1,w2,w3; bf2(w.x,w0,w1); bf2(w.y,w2,w3);
            float x0 = xp[2*kk], x1 = xp[2*kk+1];
            a0 = fmaf(x0,w0,a0); a1 = fmaf(x0,w1,a1);
            a2 = fmaf(x0,w2,a2); a3 = fmaf(x0,w3,a3);
            a4 = fmaf(x1,w0,a4); a5 = fmaf(x1,w1,a5);
            a6 = fmaf(x1,w2,a6); a7 = fmaf(x1,w3,a7);
        }
        float4* r0 = (float4*)&red[(0*16 + ks)*260 + 4*jg];
        float4* r1 = (float4*)&red[(1*16 + ks)*260 + 4*jg];
        *r0 = make_float4(a0,a1,a2,a3);
        *r1 = make_float4(a4,a5,a6,a7);
    }
    __syncthreads();
    if (tid < 512) {
        int b = tid >> 8, j = tid & 255;
        float s = e_b1[j];
        #pragma unroll
        for (int si = 0; si < 16; ++si) s += red[(b*16+si)*260 + j];
        h1[j*2 + b] = leakyf(s);
    }
    __syncthreads();

    // ================= encoder L2: K=256, N=256, S=16 (16 k each) ========
    {
        int jg = tid & 63, ks = tid >> 6;
        const uint2* p = (const uint2*)(ws + WS_W2) + (ks * 16) * 64 + jg;
        const float* xp = h1 + (ks * 16) * 2;
        float a0=0,a1=0,a2=0,a3=0,a4=0,a5=0,a6=0,a7=0;
        #pragma unroll
        for (int kk = 0; kk < 16; ++kk, p += 64) {
            uint2 w = *p;
            float w0,w1,w2,w3; bf2(w.x,w0,w1); bf2(w.y,w2,w3);
            float x0 = xp[2*kk], x1 = xp[2*kk+1];
            a0 = fmaf(x0,w0,a0); a1 = fmaf(x0,w1,a1);
            a2 = fmaf(x0,w2,a2); a3 = fmaf(x0,w3,a3);
            a4 = fmaf(x1,w0,a4); a5 = fmaf(x1,w1,a5);
            a6 = fmaf(x1,w2,a6); a7 = fmaf(x1,w3,a7);
        }
        float4* r0 = (float4*)&red[(0*16 + ks)*260 + 4*jg];
        float4* r1 = (float4*)&red[(1*16 + ks)*260 + 4*jg];
        *r0 = make_float4(a0,a1,a2,a3);
        *r1 = make_float4(a4,a5,a6,a7);
    }
    __syncthreads();
    if (tid < 512) {
        int b = tid >> 8, j = tid & 255;
        float s = e_b2[j];
        #pragma unroll
        for (int si = 0; si < 16; ++si) s += red[(b*16+si)*260 + j];
        h2[j*2 + b] = leakyf(s);
    }
    __syncthreads();

    // ============ mu|lv: K=256, N=128, S=32 (8 k each), stride 132 =======
    {
        int jg = tid & 31, ks = tid >> 5;
        const uint2* p = (const uint2*)(ws + WS_ML) + (ks * 8) * 32 + jg;
        const float* xp = h2 + (ks * 8) * 2;
        float a0=0,a1=0,a2=0,a3=0,a4=0,a5=0,a6=0,a7=0;
        #pragma unroll
        for (int kk = 0; kk < 8; ++kk, p += 32) {
            uint2 w = *p;
            float w0,w1,w2,w3; bf2(w.x,w0,w1); bf2(w.y,w2,w3);
            float x0 = xp[2*kk], x1 = xp[2*kk+1];
            a0 = fmaf(x0,w0,a0); a1 = fmaf(x0,w1,a1);
            a2 = fmaf(x0,w2,a2); a3 = fmaf(x0,w3,a3);
            a4 = fmaf(x1,w0,a4); a5 = fmaf(x1,w1,a5);
            a6 = fmaf(x1,w2,a6); a7 = fmaf(x1,w3,a7);
        }
        float4* r0 = (float4*)&red[(0*32 + ks)*132 + 4*jg];
        float4* r1 = (float4*)&red[(1*32 + ks)*132 + 4*jg];
        *r0 = make_float4(a0,a1,a2,a3);
        *r1 = make_float4(a4,a5,a6,a7);
    }
    __syncthreads();
    if (tid < 256) {
        int b = tid >> 7, u = tid & 127;
        float s = (u < 64) ? b_mu[u] : b_lv[u - 64];
        #pragma unroll
        for (int si = 0; si < 32; ++si) s += red[(b*32+si)*132 + u];
        mulv[b][u] = s;
        int j = u & 63;
        out[(u < 64 ? MU_OFF : LV_OFF) + (b0 + b) * 64 + j] = s;
    }
    __syncthreads();
    if (tid < 128) {
        int b = tid >> 6, j = tid & 63;
        zs[j*2 + b] = fmaf(eps[(b0 + b) * 64 + j], expf(0.5f * mulv[b][64 + j]),
                           mulv[b][j]);
    }
    __syncthreads();

    // ============ decoder L1: K=64, N=512, S=8 (8 k each), stride 516 ====
    {
        int jg = tid & 127, ks = tid >> 7;
        const uint2* p = (const uint2*)(ws + WS_D1) + (ks * 8) * 128 + jg;
        const float* xp = zs + (ks * 8) * 2;
        float a0=0,a1=0,a2=0,a3=0,a4=0,a5=0,a6=0,a7=0;
        #pragma unroll
        for (int kk = 0; kk < 8; ++kk, p += 128) {
            uint2 w = *p;
            float w0,w1,w2,w3; bf2(w.x,w0,w1); bf2(w.y,w2,w3);
            float x0 = xp[2*kk], x1 = xp[2*kk+1];
            a0 = fmaf(x0,w0,a0); a1 = fmaf(x0,w1,a1);
            a2 = fmaf(x0,w2,a2); a3 = fmaf(x0,w3,a3);
            a4 = fmaf(x1,w0,a4); a5 = fmaf(x1,w1,a5);
            a6 = fmaf(x1,w2,a6); a7 = fmaf(x1,w3,a7);
        }
        float4* r0 = (float4*)&red[(0*8 + ks)*516 + 4*jg];
        float4* r1 = (float4*)&red[(1*8 + ks)*516 + 4*jg];
        *r0 = make_float4(a0,a1,a2,a3);
        *r1 = make_float4(a4,a5,a6,a7);
    }
    __syncthreads();
    {
        int b = tid >> 9, j = tid & 511;
        float s = d_b1[j];
        #pragma unroll
        for (int si = 0; si < 8; ++si) s += red[(b*8+si)*516 + j];
        hd1[j*2 + b] = seluf(s);
    }
    __syncthreads();

    // ============ decoder L2: K=512, N=512, S=8 (64 k each) ==============
    {
        int jg = tid & 127, ks = tid >> 7;
        const uint2* p = (const uint2*)(ws + WS_D2) + (ks * 64) * 128 + jg;
        const float* xp = hd1 + (ks * 64) * 2;
        float a0=0,a1=0,a2=0,a3=0,a4=0,a5=0,a6=0,a7=0;
        #pragma unroll 8
        for (int kk = 0; kk < 64; ++kk, p += 128) {
            uint2 w = *p;
            float w0,w1,w2,w3; bf2(w.x,w0,w1); bf2(w.y,w2,w3);
            float x0 = xp[2*kk], x1 = xp[2*kk+1];
            a0 = fmaf(x0,w0,a0); a1 = fmaf(x0,w1,a1);
            a2 = fmaf(x0,w2,a2); a3 = fmaf(x0,w3,a3);
            a4 = fmaf(x1,w0,a4); a5 = fmaf(x1,w1,a5);
            a6 = fmaf(x1,w2,a6); a7 = fmaf(x1,w3,a7);
        }
        float4* r0 = (float4*)&red[(0*8 + ks)*516 + 4*jg];
        float4* r1 = (float4*)&red[(1*8 + ks)*516 + 4*jg];
        *r0 = make_float4(a0,a1,a2,a3);
        *r1 = make_float4(a4,a5,a6,a7);
    }
    __syncthreads();
    {
        int b = tid >> 9, j = tid & 511;
        float s = d_b2[j];
        #pragma unroll
        for (int si = 0; si < 8; ++si) s += red[(b*8+si)*516 + j];
        hd2[j*2 + b] = seluf(s);
    }
    __syncthreads();

    // ============ heads: K=512, N=64(44 live), S=64 (8 k), stride 68 =====
    {
        int jg = tid & 15, ks = tid >> 4;
        const uint2* p = (const uint2*)(ws + WS_H) + (ks * 8) * 16 + jg;
        const float* xp = hd2 + (ks * 8) * 2;
        float a0=0,a1=0,a2=0,a3=0,a4=0,a5=0,a6=0,a7=0;
        #pragma unroll
        for (int kk = 0; kk < 8; ++kk, p += 16) {
            uint2 w = *p;
            float w0,w1,w2,w3; bf2(w.x,w0,w1); bf2(w.y,w2,w3);
            float x0 = xp[2*kk], x1 = xp[2*kk+1];
            a0 = fmaf(x0,w0,a0); a1 = fmaf(x0,w1,a1);
            a2 = fmaf(x0,w2,a2); a3 = fmaf(x0,w3,a3);
            a4 = fmaf(x1,w0,a4); a5 = fmaf(x1,w1,a5);
            a6 = fmaf(x1,w2,a6); a7 = fmaf(x1,w3,a7);
        }
        float4* r0 = (float4*)&red[(0*64 + ks)*68 + 4*jg];
        float4* r1 = (float4*)&red[(1*64 + ks)*68 + 4*jg];
        *r0 = make_float4(a0,a1,a2,a3);
        *r1 = make_float4(a4,a5,a6,a7);
    }
    __syncthreads();
    if (tid < 128) {
        int b = tid >> 6, u = tid & 63;
        if (u < 44) {
            float s = 0.f;
            #pragma unroll
            for (int si = 0; si < 64; ++si) s += red[(b*64+si)*68 + u];
            if (u < 40) {
                pts[b][u] = tanhf(s + p_b[u]) * 12.f + 14.f;  // CANVAS/2-MARGIN
            } else if (u < 42) {
                out[W_OFF + (b0 + b) * 2 + (u - 40)] =
                    sigmoidf(s + wd_b[u - 40]) * 2.f + 1.f;
            } else {
                out[A_OFF + (b0 + b) * 2 + (u - 42)] = sigmoidf(s + a_b[u - 42]);
            }
        }
    }
    __syncthreads();

    // scatter cp [P=2,S=3,4,2] from pts [P=2,PPP=10,2] (overlapping segments)
    if (tid < 96) {
        int bs = tid / 48, i = tid % 48;
        int p = i / 24, rem = i % 24;
        int s = rem / 8, kc = rem % 8;
        int k = kc >> 1, c = kc & 1;
        out[CP_OFF + (b0 + bs) * 48 + i] = pts[bs][p * 20 + (3 * s + k) * 2 + c];
    }
}

// Render: grid (128, 4), 256 threads. Block (b,q) -> pixel rows [7q, 7q+7).
__global__ __launch_bounds__(256) void vae_render(float* __restrict__ out)
{
    const int b   = blockIdx.x;
    const int q   = blockIdx.y;
    const int tid = threadIdx.x;

    __shared__ float2 cur[192];
    __shared__ float  wa[4];   // 0,1: width*0.5; 2,3: alpha

    if (tid < 192) {
        int p = tid / 96;
        int m = tid % 96;
        int s = m / 32;
        int t = m % 32;
        float u  = (t + 0.5f) * (1.f / 32.f);
        float v  = 1.f - u;
        float b0 = v * v * v;
        float b1 = 3.f * u * v * v;
        float b2 = 3.f * u * u * v;
        float b3 = u * u * u;
        const float* cp = out + CP_OFF + b * 48 + p * 24 + s * 8;
        float cx = b0 * cp[0] + b1 * cp[2] + b2 * cp[4] + b3 * cp[6];
        float cy = b0 * cp[1] + b1 * cp[3] + b2 * cp[5] + b3 * cp[7];
        cur[tid] = make_float2(cx, cy);
    } else if (tid < 196) {
        int i = tid - 192;
        wa[i] = (i < 2) ? 0.5f * out[W_OFF + b * 2 + i]
                        : out[A_OFF + b * 2 + (i - 2)];
    }
    __syncthreads();

    if (tid < 196) {
        int Y = tid / 28, X = tid - Y * 28;
        float px0 = X + 0.25f;
        float py0 = (7 * q + Y) + 0.25f;

        float mA[4] = {1e30f, 1e30f, 1e30f, 1e30f};
        float mB[4] = {1e30f, 1e30f, 1e30f, 1e30f};
        #pragma unroll 4
        for (int m = 0; m < 96; ++m) {
            float2 c = cur[m];
            float dx0 = px0 - c.x, dy0 = py0 - c.y;
            float dx1 = dx0 + 0.5f, dy1 = dy0 + 0.5f;
            float xx0 = dx0 * dx0, xx1 = dx1 * dx1;
            float yy0 = dy0 * dy0, yy1 = dy1 * dy1;
            mA[0] = fminf(mA[0], xx0 + yy0);
            mA[1] = fminf(mA[1], xx1 + yy0);
            mA[2] = fminf(mA[2], xx0 + yy1);
            mA[3] = fminf(mA[3], xx1 + yy1);
        }
        #pragma unroll 4
        for (int m = 96; m < 192; ++m) {
            float2 c = cur[m];
            float dx0 = px0 - c.x, dy0 = py0 - c.y;
            float dx1 = dx0 + 0.5f, dy1 = dy0 + 0.5f;
            float xx0 = dx0 * dx0, xx1 = dx1 * dx1;
            float yy0 = dy0 * dy0, yy1 = dy1 * dy1;
            mB[0] = fminf(mB[0], xx0 + yy0);
            mB[1] = fminf(mB[1], xx1 + yy0);
            mB[2] = fminf(mB[2], xx0 + yy1);
            mB[3] = fminf(mB[3], xx1 + yy1);
        }

        const float w0 = wa[0], w1 = wa[1], a0 = wa[2], a1 = wa[3];
        float v = 0.f;
        #pragma unroll
        for (int s = 0; s < 4; ++s) {
            float d0 = sqrtf(mA[s] + 1e-12f);
            float d1 = sqrtf(mB[s] + 1e-12f);
            float c0 = a0 / (1.f + expf(-2.f * (w0 - d0)));
            float c1 = a1 / (1.f + expf(-2.f * (w1 - d1)));
            v += (1.f - c0) * (1.f - c1);
        }
        out[REND_OFF + b * 784 + (7 * q + Y) * 28 + X] = 1.f - 0.25f * v;
    }
}

extern "C" void kernel_launch(void* const* d_in, const int* in_sizes, int n_in,
                              void* d_out, int out_size, void* d_ws, size_t ws_size,
                              hipStream_t stream) {
    const float* x    = (const float*)d_in[0];
    const float* eps  = (const float*)d_in[1];
    const float* e_w1 = (const float*)d_in[2];
    const float* e_b1 = (const float*)d_in[3];
    const float* e_w2 = (const float*)d_in[4];
    const float* e_b2 = (const float*)d_in[5];
    const float* w_mu = (const float*)d_in[6];
    const float* b_mu = (const float*)d_in[7];
    const float* w_lv = (const float*)d_in[8];
    const float* b_lv = (const float*)d_in[9];
    const float* d_w1 = (const float*)d_in[10];
    const float* d_b1 = (const float*)d_in[11];
    const float* d_w2 = (const float*)d_in[12];
    const float* d_b2 = (const float*)d_in[13];
    const float* p_w  = (const float*)d_in[14];
    const float* p_b  = (const float*)d_in[15];
    const float* wd_w = (const float*)d_in[16];
    const float* wd_b = (const float*)d_in[17];
    const float* a_w  = (const float*)d_in[18];
    const float* a_b  = (const float*)d_in[19];
    float* out = (float*)d_out;
    __hip_bfloat16* ws = (__hip_bfloat16*)d_ws;

    hipLaunchKernelGGL(conv_w, dim3(2448), dim3(256), 0, stream,
                       e_w1, e_w2, w_mu, w_lv, d_w1, d_w2, p_w, wd_w, a_w, ws);
    hipLaunchKernelGGL(vae_mlp, dim3(64), dim3(1024), 0, stream,
                       x, eps, e_b1, e_b2, b_mu, b_lv, d_b1, d_b2,
                       p_b, wd_b, a_b, ws, out);
    hipLaunchKernelGGL(vae_render, dim3(128, 4), dim3(256), 0, stream, out);
}